// Round 1
// baseline (974.606 us; speedup 1.0000x reference)
//
#include <hip/hip_runtime.h>

#define N_SEL 192
#define N_PTS 2048
#define C_IN 256
#define C_OUT 256
#define N_TILES 8

#define BM 128
#define BN 128
#define BK 64
#define LDA 72  // bf16 elems per LDS row: 64 + 8 pad -> 144 B row stride (9x16B)

typedef __attribute__((ext_vector_type(8))) short short8;
typedef __attribute__((ext_vector_type(4))) float f32x4;

__device__ __forceinline__ unsigned short f2bf(float f) {
    union { float f; unsigned u; } v; v.f = f;
    unsigned r = v.u + 0x7fffu + ((v.u >> 16) & 1u);  // RNE (inputs are finite)
    return (unsigned short)(r >> 16);
}

// Kernel 1: wT_bf16[s][n][k] = bf16(weight[indices[s], t, k, n])
// One block per (s, 64x64 tile). LDS transpose keeps both sides coalesced.
__global__ __launch_bounds__(256) void gather_transpose_w(
    const float* __restrict__ weight, const int* __restrict__ indices,
    const int* __restrict__ t_ptr, unsigned short* __restrict__ wT) {
    __shared__ float tile[64][65];  // +1 pad: column reads conflict-free
    const int tid = threadIdx.x;
    const int b   = blockIdx.x;
    const int s   = b >> 4;
    const int tl  = b & 15;
    const int k0  = (tl >> 2) * 64;
    const int n0  = (tl & 3) * 64;
    const int t   = t_ptr[0];
    const int ch  = indices[s];
    const float* wsrc = weight + (size_t)(ch * N_TILES + t) * C_IN * C_OUT;

    // read 64x64 [k][n] tile, coalesced float4 rows
    {
        const int c4 = tid & 15;
        const int rb = tid >> 4;  // 0..15
        for (int p = 0; p < 4; ++p) {
            int r = p * 16 + rb;
            float4 v = *(const float4*)(wsrc + (size_t)(k0 + r) * C_OUT + n0 + c4 * 4);
            tile[r][c4 * 4 + 0] = v.x; tile[r][c4 * 4 + 1] = v.y;
            tile[r][c4 * 4 + 2] = v.z; tile[r][c4 * 4 + 3] = v.w;
        }
    }
    __syncthreads();
    // write transposed [n][k], bf16, coalesced 16B rows
    {
        const int c8 = tid & 7;
        const int nb = tid >> 3;  // 0..31
        for (int p = 0; p < 2; ++p) {
            int n = p * 32 + nb;
            unsigned short h[8];
            for (int j = 0; j < 8; ++j) h[j] = f2bf(tile[c8 * 8 + j][n]);
            uint4 o;
            o.x = (unsigned)h[0] | ((unsigned)h[1] << 16);
            o.y = (unsigned)h[2] | ((unsigned)h[3] << 16);
            o.z = (unsigned)h[4] | ((unsigned)h[5] << 16);
            o.w = (unsigned)h[6] | ((unsigned)h[7] << 16);
            *(uint4*)(wT + (size_t)(s * C_OUT + n0 + n) * C_IN + k0 + c8 * 8) = o;
        }
    }
}

// Kernel 2: out[s][m][n] = sum_k x[s][m][k] * W[k][n] + bias[n]
// Block tile 128x128, BK=64, 256 threads = 4 waves (2x2), wave tile 64x64
// via 4x4 grid of v_mfma_f32_16x16x32_bf16. A converted fp32->bf16 on the fly.
__global__ __launch_bounds__(256) void adaptive_gemm(
    const float* __restrict__ x, const unsigned short* __restrict__ wT,
    const float* __restrict__ bias, const int* __restrict__ indices,
    const int* __restrict__ t_ptr, float* __restrict__ out) {
    __shared__ unsigned short As[BM * LDA];  // A[m][k] bf16, row stride 144 B
    __shared__ unsigned short Bs[BN * LDA];  // B^T[n][k] bf16

    const int tid = threadIdx.x;
    const int bid = blockIdx.x;
    const int nt  = bid & 1;          // n-tile fast: A-tile L2 reuse between the 2 n-blocks
    const int mt  = (bid >> 1) & 15;  // then m-tile: W reuse within a channel
    const int s   = bid >> 5;

    const int m0 = mt * BM;
    const int n0 = nt * BN;

    const int lane = tid & 63;
    const int wave = tid >> 6;
    const int wm   = (wave >> 1) * 64;
    const int wn   = (wave & 1) * 64;
    const int quad = lane >> 4;
    const int l15  = lane & 15;

    const float*          xbase = x  + (size_t)(s * N_PTS + m0) * C_IN;
    const unsigned short* wbase = wT + (size_t)(s * C_OUT + n0) * C_IN;

    f32x4 acc[4][4];
    for (int i = 0; i < 4; ++i)
        for (int j = 0; j < 4; ++j) {
            f32x4 z = {0.0f, 0.0f, 0.0f, 0.0f};
            acc[i][j] = z;
        }

    const int a_m  = tid >> 4;  // 16 rows/pass, float4 lane-contiguous per row
    const int a_f4 = tid & 15;
    const int b_n  = tid >> 3;  // 32 rows/pass, 16B lane-contiguous per row
    const int b_c8 = tid & 7;

    for (int kb = 0; kb < C_IN / BK; ++kb) {
        const int K0 = kb * BK;
        // stage A: 128x64 fp32 -> bf16 LDS (8 passes x 16 rows)
        for (int p = 0; p < 8; ++p) {
            int m = p * 16 + a_m;
            float4 v = *(const float4*)(xbase + (size_t)m * C_IN + K0 + a_f4 * 4);
            ushort4 h;
            h.x = f2bf(v.x); h.y = f2bf(v.y); h.z = f2bf(v.z); h.w = f2bf(v.w);
            *(ushort4*)(&As[m * LDA + a_f4 * 4]) = h;
        }
        // stage B: 128x64 bf16 (4 passes x 32 rows), straight 16B copies
        for (int p = 0; p < 4; ++p) {
            int n = p * 32 + b_n;
            uint4 v = *(const uint4*)(wbase + (size_t)n * C_IN + K0 + b_c8 * 8);
            *(uint4*)(&Bs[n * LDA + b_c8 * 8]) = v;
        }
        __syncthreads();

        for (int ko = 0; ko < BK; ko += 32) {
            short8 af[4], bf[4];
            for (int i = 0; i < 4; ++i)
                af[i] = *(const short8*)(&As[(wm + i * 16 + l15) * LDA + ko + quad * 8]);
            for (int j = 0; j < 4; ++j)
                bf[j] = *(const short8*)(&Bs[(wn + j * 16 + l15) * LDA + ko + quad * 8]);
            for (int i = 0; i < 4; ++i)
                for (int j = 0; j < 4; ++j)
                    acc[i][j] = __builtin_amdgcn_mfma_f32_16x16x32_bf16(
                        af[i], bf[j], acc[i][j], 0, 0, 0);
        }
        __syncthreads();
    }

    // epilogue: + bias, store fp32. C/D layout: col=lane&15, row=quad*4+r.
    const int t  = t_ptr[0];
    const int ch = indices[s];
    const float* bptr = bias + (size_t)(ch * N_TILES + t) * C_OUT;
    for (int j = 0; j < 4; ++j) {
        int col = n0 + wn + j * 16 + l15;
        float bv = bptr[col];
        for (int i = 0; i < 4; ++i) {
            int mrow = m0 + wm + i * 16 + quad * 4;
            for (int r = 0; r < 4; ++r)
                out[(size_t)(s * N_PTS + mrow + r) * C_OUT + col] = acc[i][j][r] + bv;
        }
    }
}

extern "C" void kernel_launch(void* const* d_in, const int* in_sizes, int n_in,
                              void* d_out, int out_size, void* d_ws, size_t ws_size,
                              hipStream_t stream) {
    const float* x       = (const float*)d_in[0];
    const float* weight  = (const float*)d_in[1];
    const float* bias    = (const float*)d_in[2];
    const int*   indices = (const int*)d_in[3];
    const int*   t_ptr   = (const int*)d_in[4];
    float*       out     = (float*)d_out;
    unsigned short* wT   = (unsigned short*)d_ws;  // 192*256*256*2 = 25.2 MB

    gather_transpose_w<<<N_SEL * 16, 256, 0, stream>>>(weight, indices, t_ptr, wT);
    adaptive_gemm<<<N_SEL * 32, 256, 0, stream>>>(x, wT, bias, indices, t_ptr, out);
}